// Round 1
// 278.035 us; speedup vs baseline: 1.0048x; 1.0048x over previous
//
#include <hip/hip_runtime.h>
#include <math.h>

#define D_MODEL 2048
#define KB_ 64
#define NCHUNK 32

typedef __bf16 bf16;
typedef __attribute__((ext_vector_type(8))) __bf16 bf16x8;
typedef __attribute__((ext_vector_type(4))) __bf16 bf16x4;
typedef __attribute__((ext_vector_type(4))) float f32x4;

// ---- workspace layout (float offsets) ----
#define OFF_COEFFS 0                            // [32][64][2048]
#define OFF_NSQ    (32 * 64 * 2048)             // [32][64][32] per-dtile sumsq partials
#define OFF_NORMS  (OFF_NSQ + 32 * 64 * 32)     // [32][64]
#define OFF_VR     (OFF_NORMS + 2048)           // [2048]
#define OFF_VI     (OFF_VR + 2048)              // [2048]  (contiguous after VR!)
#define OFF_CTX    (OFF_VI + 2048)              // [2048]
#define OFF_CHEB2  (OFF_CTX + 2048)             // 32768 bf16 = 16384 floats
#define OFF_HM     (OFF_CHEB2 + 16384)          // [8192][2048] bf16 = 4194304 floats

// ---------------------------------------------------------------------------
// K0: fused streaming pre-pass.
//  blocks [0,8192):   hm[token][d] = bf16(0.5*(scan0+scan1))   (one token/block)
//  blocks [8192,8208): cheb2 = bf16(cheby)
//  block  8208:       zero vr||vi (4096 floats)
// ---------------------------------------------------------------------------
__global__ __launch_bounds__(256) void k0_prep(
    const float* __restrict__ scan, const float* __restrict__ cheby,
    bf16* __restrict__ hm, bf16* __restrict__ cheb2, float* __restrict__ vzero)
{
  const int b = blockIdx.x;
  const int t = threadIdx.x;
  if (b < 8192) {
    const float* p0 = scan + b * 2048 + t * 8;
    const float* p1 = p0 + 8192 * 2048;
    float4 a0 = *(const float4*)(p0);
    float4 a1 = *(const float4*)(p0 + 4);
    float4 b0 = *(const float4*)(p1);
    float4 b1 = *(const float4*)(p1 + 4);
    bf16x8 e = {(bf16)(0.5f * (a0.x + b0.x)), (bf16)(0.5f * (a0.y + b0.y)),
                (bf16)(0.5f * (a0.z + b0.z)), (bf16)(0.5f * (a0.w + b0.w)),
                (bf16)(0.5f * (a1.x + b1.x)), (bf16)(0.5f * (a1.y + b1.y)),
                (bf16)(0.5f * (a1.z + b1.z)), (bf16)(0.5f * (a1.w + b1.w))};
    *(bf16x8*)(hm + b * 2048 + t * 8) = e;
  } else if (b < 8208) {
    int idx = (b - 8192) * 2048 + t * 8;
    float4 c0 = *(const float4*)(cheby + idx);
    float4 c1 = *(const float4*)(cheby + idx + 4);
    bf16x8 e = {(bf16)c0.x, (bf16)c0.y, (bf16)c0.z, (bf16)c0.w,
                (bf16)c1.x, (bf16)c1.y, (bf16)c1.z, (bf16)c1.w};
    *(bf16x8*)(cheb2 + idx) = e;
  } else {
    float4 z = make_float4(0.f, 0.f, 0.f, 0.f);
#pragma unroll
    for (int i = 0; i < 4; ++i)
      *(float4*)(vzero + t * 16 + i * 4) = z;
  }
}

// ---------------------------------------------------------------------------
// K1: window form. Block (dt, c): coeffs[c][band][d0..d0+64) =
//   scale * sum_{n=0..511} cheby[band][n] * hm_window_c[n][d]
// Staging now reads L3-resident bf16 hm (half the bytes, no mean/cvt VALU).
// ---------------------------------------------------------------------------
__global__ __launch_bounds__(256) void k1_mfma(
    const bf16* __restrict__ hm, const float* __restrict__ buf,
    const bf16* __restrict__ cheb2, float* __restrict__ coeffs,
    float* __restrict__ nsq_part)
{
  __shared__ bf16 Bs[64 * 72];   // [d][72]: 64 n-slots + pad

  const int t = threadIdx.x;
  const int dt = blockIdx.x;     // 0..31 d-tile
  const int c  = blockIdx.y;     // 0..31 window
  const int w = t >> 6, lane = t & 63;
  const int quad = lane >> 4, r16 = lane & 15;
  const int d0 = dt * 64;
  const int n0 = (t >> 4) * 4;   // staging: 4 n-rows per thread
  const int d4 = (t & 15) * 4;   // staging: 4 d-cols per thread

  f32x4 acc[4];
#pragma unroll
  for (int tn = 0; tn < 4; ++tn) acc[tn] = (f32x4){0.f, 0.f, 0.f, 0.f};

  for (int nb = 0; nb < 8; ++nb) {
    // A-fragments straight from L2-resident bf16 cheby
    const bf16* abase = cheb2 + (w * 16 + r16) * 512 + nb * 64 + quad * 8;
    bf16x8 a0 = *(const bf16x8*)(abase);
    bf16x8 a1 = *(const bf16x8*)(abase + 32);

    // B staging: rows n0..n0+3, cols d4..d4+3 of this 64x64 slice
    bf16x4 rowv[4];
    if (c == 0 && nb < 4) {
      const float* bp = buf + (256 + nb * 64 + n0) * 2048 + d0 + d4;
#pragma unroll
      for (int i = 0; i < 4; ++i) {
        float4 v = *(const float4*)(bp + i * 2048);
        rowv[i] = (bf16x4){(bf16)v.x, (bf16)v.y, (bf16)v.z, (bf16)v.w};
      }
    } else {
      const bf16* hp = hm + (c * 256 - 256 + nb * 64 + n0) * 2048 + d0 + d4;
#pragma unroll
      for (int i = 0; i < 4; ++i)
        rowv[i] = *(const bf16x4*)(hp + i * 2048);
    }
    __syncthreads();   // previous iteration's reads done before overwrite
#pragma unroll
    for (int x = 0; x < 4; ++x) {
      bf16x4 e = {rowv[0][x], rowv[1][x], rowv[2][x], rowv[3][x]};
      *(bf16x4*)(Bs + (d4 + x) * 72 + n0) = e;
    }
    __syncthreads();

#pragma unroll
    for (int ks = 0; ks < 2; ++ks) {
      bf16x8 a = ks ? a1 : a0;
#pragma unroll
      for (int tn = 0; tn < 4; ++tn) {
        bf16x8 bfr = *(const bf16x8*)(Bs + (tn * 16 + r16) * 72 + ks * 32 + quad * 8);
        acc[tn] = __builtin_amdgcn_mfma_f32_16x16x32_bf16(a, bfr, acc[tn], 0, 0, 0);
      }
    }
  }

  // epilogue: scale, store, per-band sumsq partial
  const float scale = 2.0f / 512.0f;
  float sq[4] = {0.f, 0.f, 0.f, 0.f};
#pragma unroll
  for (int tn = 0; tn < 4; ++tn) {
#pragma unroll
    for (int rr = 0; rr < 4; ++rr) {
      int band = w * 16 + quad * 4 + rr;
      float sc = (band == 0) ? scale * 0.5f : scale;
      float v = acc[tn][rr] * sc;
      coeffs[(c * 64 + band) * 2048 + d0 + tn * 16 + r16] = v;
      sq[rr] += v * v;
    }
  }
#pragma unroll
  for (int off = 8; off > 0; off >>= 1) {
#pragma unroll
    for (int rr = 0; rr < 4; ++rr) sq[rr] += __shfl_down(sq[rr], off);
  }
  if (r16 == 0) {
#pragma unroll
    for (int rr = 0; rr < 4; ++rr)
      nsq_part[(c * 64 + w * 16 + quad * 4 + rr) * 32 + dt] = sq[rr];
  }
}

// ---------------------------------------------------------------------------
// KD: delta[k] = ||coeffs[31][k] - coeffs[30][k]|| -> dout[2048+k]
// ---------------------------------------------------------------------------
__global__ __launch_bounds__(256) void kd_delta(
    const float* __restrict__ coeffs, float* __restrict__ dout)
{
  const int k = blockIdx.x, tid = threadIdx.x;
  const float* p1 = coeffs + (31 * 64 + k) * 2048;
  const float* p0 = coeffs + (30 * 64 + k) * 2048;
  float s = 0.f;
#pragma unroll
  for (int i = 0; i < 2; ++i) {
    float4 a = *(const float4*)(p1 + tid * 4 + i * 1024);
    float4 b = *(const float4*)(p0 + tid * 4 + i * 1024);
    float x = a.x - b.x, y = a.y - b.y, z = a.z - b.z, ww = a.w - b.w;
    s += x * x + y * y + z * z + ww * ww;
  }
  for (int o = 32; o > 0; o >>= 1) s += __shfl_down(s, o, 64);
  __shared__ float red[4];
  if ((tid & 63) == 0) red[tid >> 6] = s;
  __syncthreads();
  if (tid == 0) dout[D_MODEL + k] = sqrtf(red[0] + red[1] + red[2] + red[3]);
}

// ---------------------------------------------------------------------------
// K3: finalize norms (from nsq_part) + EMA-weighted bind, atomically
// accumulated into vr/vi. grid (8, 32) = 256 blocks, 1 d per thread.
// ---------------------------------------------------------------------------
__global__ __launch_bounds__(256) void k3_bind(
    const float* __restrict__ coeffs, const float* __restrict__ nsq_part,
    const float* __restrict__ rr, const float* __restrict__ ri,
    float* __restrict__ vr, float* __restrict__ vi,
    float* __restrict__ norms)
{
  __shared__ float inv_s[64];
  const int tid = threadIdx.x;
  const int c = blockIdx.y;
  if (tid < 64) {
    float s = 0.f;
#pragma unroll
    for (int dt = 0; dt < 32; ++dt) s += nsq_part[(c * 64 + tid) * 32 + dt];
    float nrm = fmaxf(sqrtf(s), 1e-12f);
    inv_s[tid] = 1.0f / nrm;
    if (blockIdx.x == 0) norms[c * 64 + tid] = nrm;
  }
  __syncthreads();
  const int d = blockIdx.x * 256 + tid;
  const float wc = 0.1f * powf(0.9f, (float)(31 - c));
  float ar = 0.f, ai = 0.f;
#pragma unroll 8
  for (int k = 0; k < KB_; ++k) {
    float cf = coeffs[(c * 64 + k) * 2048 + d] * inv_s[k];
    ar += cf * rr[k * D_MODEL + d];
    ai += cf * ri[k * D_MODEL + d];
  }
  atomicAdd(&vr[d], wc * ar);
  atomicAdd(&vi[d], wc * ai);
}

// ---------------------------------------------------------------------------
// K4: cnorms EMA + top-8 (redundant per block, cheap); vr/vi -> d_out; ctx
// ---------------------------------------------------------------------------
__global__ __launch_bounds__(256) void k4_ctx(
    const float* __restrict__ norms, const float* __restrict__ vr,
    const float* __restrict__ vi, const float* __restrict__ rr,
    const float* __restrict__ ri, const float* __restrict__ wbands,
    float* __restrict__ dout, float* __restrict__ ctx)
{
  __shared__ float cn_s[64];
  __shared__ int top_s[8];
  __shared__ float wgt_s[8];
  const int tid = threadIdx.x;
  const int d = blockIdx.x * 256 + tid;
  if (tid < 64) {
    float s = 0.f;
    for (int c = 0; c < NCHUNK; ++c) s = 0.9f * s + 0.1f * norms[c * 64 + tid];
    cn_s[tid] = fmaxf(s, 1e-12f);
  }
  __syncthreads();
  if (tid == 0) {
    unsigned long long taken = 0ULL;
    for (int jj = 0; jj < 8; ++jj) {
      float best = -1.f;
      int bi = 0;
      for (int k = 0; k < 64; ++k) {
        float dv = dout[D_MODEL + k];
        if (!((taken >> k) & 1ULL) && dv > best) { best = dv; bi = k; }
      }
      taken |= (1ULL << bi);
      top_s[jj] = bi;
      wgt_s[jj] = log1pf(expf(wbands[bi]));  // softplus
    }
  }
  __syncthreads();
  float sr = vr[d];
  float si = vi[d];
  dout[D_MODEL + KB_ + d] = sr;
  dout[D_MODEL + KB_ + D_MODEL + d] = si;
  float cx = 0.f;
#pragma unroll
  for (int jj = 0; jj < 8; ++jj) {
    int k = top_s[jj];
    cx += wgt_s[jj] * (sr * rr[k * D_MODEL + d] + si * ri[k * D_MODEL + d]) * cn_s[k];
  }
  ctx[d] = cx;
}

// K5b: out[d] = sigmoid(gate) * sum_e ctx[e]*Wp[d][e]; one wave per row
__global__ __launch_bounds__(256) void k5b_gemv(
    const float* __restrict__ Wp, const float* __restrict__ ctx,
    const float* __restrict__ gate, float* __restrict__ dout)
{
  const int tid = threadIdx.x;
  const int lane = tid & 63;
  const int w = tid >> 6;
  const int row = blockIdx.x * 4 + w;
  const float* p = Wp + row * D_MODEL;
  float s = 0.f;
#pragma unroll
  for (int i = 0; i < 8; ++i) {
    int e = lane * 4 + i * 256;
    float4 wv = *(const float4*)(p + e);
    float4 cv = *(const float4*)(ctx + e);
    s += wv.x * cv.x + wv.y * cv.y + wv.z * cv.z + wv.w * cv.w;
  }
  for (int o = 32; o > 0; o >>= 1) s += __shfl_down(s, o, 64);
  if (lane == 0) {
    float sig = 1.f / (1.f + expf(-gate[0]));
    dout[row] = s * sig;
  }
}

extern "C" void kernel_launch(void* const* d_in, const int* in_sizes, int n_in,
                              void* d_out, int out_size, void* d_ws, size_t ws_size,
                              hipStream_t stream) {
  const float* scan  = (const float*)d_in[0];
  const float* buf   = (const float*)d_in[1];
  const float* rr    = (const float*)d_in[2];
  const float* ri    = (const float*)d_in[3];
  const float* wb    = (const float*)d_in[4];
  const float* Wp    = (const float*)d_in[5];
  const float* gate  = (const float*)d_in[6];
  const float* cheby = (const float*)d_in[7];
  float* out = (float*)d_out;
  float* ws = (float*)d_ws;

  float* coeffs   = ws + OFF_COEFFS;
  float* nsq_part = ws + OFF_NSQ;
  float* norms    = ws + OFF_NORMS;
  float* vr       = ws + OFF_VR;
  float* vi       = ws + OFF_VI;
  float* ctx      = ws + OFF_CTX;
  bf16*  cheb2    = (bf16*)(ws + OFF_CHEB2);
  bf16*  hm       = (bf16*)(ws + OFF_HM);

  k0_prep<<<8209, 256, 0, stream>>>(scan, cheby, hm, cheb2, vr);
  k1_mfma<<<dim3(32, 32), 256, 0, stream>>>(hm, buf, cheb2, coeffs, nsq_part);
  kd_delta<<<64, 256, 0, stream>>>(coeffs, out);
  k3_bind<<<dim3(8, NCHUNK), 256, 0, stream>>>(coeffs, nsq_part, rr, ri,
                                               vr, vi, norms);
  k4_ctx<<<8, 256, 0, stream>>>(norms, vr, vi, rr, ri, wb, out, ctx);
  k5b_gemv<<<512, 256, 0, stream>>>(Wp, ctx, gate, out);
}